// Round 1
// baseline (178.312 us; speedup 1.0000x reference)
//
#include <hip/hip_runtime.h>
#include <hip/hip_bf16.h>

#define B_   64
#define NW_  256
#define H_   768

#define ALPHA_BETA     (0.1f / 768.0f)
#define ONE_MINUS_BETA 0.9f
#define K1_            0.1f
#define BP_            1.2f
#define AVDL_          50.0f

typedef __bf16 bf16x8 __attribute__((ext_vector_type(8)));
typedef float  f32x4  __attribute__((ext_vector_type(4)));

// ---------------------------------------------------------------------------
// GEMM: S[b,q,d] = dot(maskedQ[b,q,:], maskedD[b,d,:]) over H=768.
// One wave per block; each wave computes a 64x64 tile via 4x4 MFMA
// 16x16x32 bf16 tiles. Inline f32->bf16 conversion during LDS staging.
// Grid: (4 n-tiles, 4 m-tiles, 64 batches) = 1024 blocks of 64 threads.
// ---------------------------------------------------------------------------
__global__ __launch_bounds__(64) void gemm_kernel(
    const float* __restrict__ q_rep, const float* __restrict__ d_rep,
    const int* __restrict__ q_ids, const int* __restrict__ d_ids,
    float* __restrict__ S)
{
    // LDS tiles: [buf][row 64][k 32 + pad 8] bf16.  Row stride 80B: 16B-aligned,
    // <=2-way bank conflicts on both b128 writes and frag reads (free per m136).
    __shared__ __align__(16) __bf16 As[2][64][40];
    __shared__ __align__(16) __bf16 Bs[2][64][40];

    const int lane = threadIdx.x;       // 0..63
    const int b  = blockIdx.z;
    const int m0 = blockIdx.y * 64;
    const int n0 = blockIdx.x * 64;

    const int rq  = lane >> 2;          // 0..15 (row within 16-row group)
    const int seg = lane & 3;           // 0..3  (8-float segment within BK=32)

    // Null masks for the rows this lane stages (constant across k-loop).
    float mA[4], mB[4];
#pragma unroll
    for (int it = 0; it < 4; ++it) {
        const int row = it * 16 + rq;
        int4 qa = *(const int4*)(q_ids + ((size_t)b * NW_ + m0 + row) * 4);
        mA[it] = (qa.x == 0 && qa.y == 0 && qa.z == 0 && qa.w == 0) ? 0.f : 1.f;
        int4 da = *(const int4*)(d_ids + ((size_t)b * NW_ + n0 + row) * 4);
        mB[it] = (da.x == 0 && da.y == 0 && da.z == 0 && da.w == 0) ? 0.f : 1.f;
    }

    const float* Abase = q_rep + ((size_t)b * NW_ + m0) * H_;
    const float* Bbase = d_rep + ((size_t)b * NW_ + n0) * H_;

    f32x4 acc[4][4];
#pragma unroll
    for (int i = 0; i < 4; ++i)
#pragma unroll
        for (int j = 0; j < 4; ++j)
            acc[i][j] = (f32x4){0.f, 0.f, 0.f, 0.f};

    float4 ra[8], rb[8];   // prefetch registers: 4 row-groups x 2 float4 each

    auto load_tiles = [&](int k0) {
#pragma unroll
        for (int it = 0; it < 4; ++it) {
            const float* pa = Abase + (size_t)(it * 16 + rq) * H_ + k0 + seg * 8;
            ra[it * 2]     = *(const float4*)pa;
            ra[it * 2 + 1] = *(const float4*)(pa + 4);
            const float* pb = Bbase + (size_t)(it * 16 + rq) * H_ + k0 + seg * 8;
            rb[it * 2]     = *(const float4*)pb;
            rb[it * 2 + 1] = *(const float4*)(pb + 4);
        }
    };

    auto write_tiles = [&](int buf) {
#pragma unroll
        for (int it = 0; it < 4; ++it) {
            const int row = it * 16 + rq;
            float4 x = ra[it * 2], y = ra[it * 2 + 1];
            float m = mA[it];
            bf16x8 va;
            va[0] = (__bf16)(x.x * m); va[1] = (__bf16)(x.y * m);
            va[2] = (__bf16)(x.z * m); va[3] = (__bf16)(x.w * m);
            va[4] = (__bf16)(y.x * m); va[5] = (__bf16)(y.y * m);
            va[6] = (__bf16)(y.z * m); va[7] = (__bf16)(y.w * m);
            *(bf16x8*)&As[buf][row][seg * 8] = va;

            float4 u = rb[it * 2], v = rb[it * 2 + 1];
            float n = mB[it];
            bf16x8 vb;
            vb[0] = (__bf16)(u.x * n); vb[1] = (__bf16)(u.y * n);
            vb[2] = (__bf16)(u.z * n); vb[3] = (__bf16)(u.w * n);
            vb[4] = (__bf16)(v.x * n); vb[5] = (__bf16)(v.y * n);
            vb[6] = (__bf16)(v.z * n); vb[7] = (__bf16)(v.w * n);
            *(bf16x8*)&Bs[buf][row][seg * 8] = vb;
        }
    };

    const int fr = lane & 15;           // frag row within 16x16 tile
    const int fk = (lane >> 4) * 8;     // frag k offset (quad*8)

    auto compute = [&](int buf) {
        bf16x8 af[4], bfr[4];
#pragma unroll
        for (int t = 0; t < 4; ++t) {
            af[t]  = *(bf16x8*)&As[buf][t * 16 + fr][fk];
            bfr[t] = *(bf16x8*)&Bs[buf][t * 16 + fr][fk];
        }
#pragma unroll
        for (int i = 0; i < 4; ++i)
#pragma unroll
            for (int j = 0; j < 4; ++j)
                acc[i][j] = __builtin_amdgcn_mfma_f32_16x16x32_bf16(
                    af[i], bfr[j], acc[i][j], 0, 0, 0);
    };

    // Prologue: stage chunk 0.
    load_tiles(0);
    write_tiles(0);
    int buf = 0;

    // K = 768 = 24 chunks of 32.
    for (int kc = 1; kc < 24; ++kc) {
        __syncthreads();           // LDS writes of `buf` visible; vmcnt already 0
        load_tiles(kc * 32);       // prefetch next chunk (stays in flight over MFMAs)
        compute(buf);
        write_tiles(buf ^ 1);      // vmcnt wait lands here, after the MFMAs
        buf ^= 1;
    }
    __syncthreads();
    compute(buf);

    // Epilogue: C layout col = lane&15, row = (lane>>4)*4 + reg.
    const int cn = lane & 15;
    const int rb4 = (lane >> 4) * 4;
#pragma unroll
    for (int i = 0; i < 4; ++i)
#pragma unroll
        for (int j = 0; j < 4; ++j)
#pragma unroll
            for (int r = 0; r < 4; ++r) {
                const int m = m0 + i * 16 + rb4 + r;
                const int n = n0 + j * 16 + cn;
                S[((size_t)b * NW_ + m) * NW_ + n] = acc[i][j][r];
            }
}

// ---------------------------------------------------------------------------
// Score reduce: one wave per (b,q). etdf = AB*sum_d(S*tf) + 0.9*sum_d(em*tf);
// dl = sum_d tf; dtw = 1.1*etdf/(etdf + K1*(1-Bp+Bp*dl/AVDL) + 1e-8).
// Writes qtw*dtw per (b,q) into ws.
// ---------------------------------------------------------------------------
__global__ __launch_bounds__(64) void score_kernel(
    const float* __restrict__ S, const int* __restrict__ q_ids,
    const int* __restrict__ d_ids, const int* __restrict__ d_tfs,
    const float* __restrict__ qtw, float* __restrict__ ws_dtw)
{
    const int lane = threadIdx.x;
    const int q = blockIdx.x;
    const int b = blockIdx.y;

    int4 qk = *(const int4*)(q_ids + ((size_t)b * NW_ + q) * 4);

    const float* Srow = S + ((size_t)b * NW_ + q) * NW_;
    float4 sv  = *(const float4*)(Srow + lane * 4);
    int4  tf4  = *(const int4*)(d_tfs + (size_t)b * NW_ + lane * 4);
    const int4* dk = (const int4*)(d_ids + ((size_t)b * NW_ + lane * 4) * 4);

    float svv[4] = {sv.x, sv.y, sv.z, sv.w};
    float tfv[4] = {(float)tf4.x, (float)tf4.y, (float)tf4.z, (float)tf4.w};

    float s1 = 0.f, s2 = 0.f, s3 = 0.f;
#pragma unroll
    for (int j = 0; j < 4; ++j) {
        int4 dj = dk[j];
        bool em = (dj.x == qk.x) && (dj.y == qk.y) &&
                  (dj.z == qk.z) && (dj.w == qk.w);
        s1 += svv[j] * tfv[j];
        s2 += em ? tfv[j] : 0.f;
        s3 += tfv[j];
    }
#pragma unroll
    for (int off = 32; off; off >>= 1) {
        s1 += __shfl_xor(s1, off);
        s2 += __shfl_xor(s2, off);
        s3 += __shfl_xor(s3, off);
    }
    if (lane == 0) {
        float etdf = ALPHA_BETA * s1 + ONE_MINUS_BETA * s2;
        float dl = s3;
        float c = K1_ * (1.f - BP_ + BP_ * dl / AVDL_);
        float dtw = (etdf * (1.f + K1_)) / (etdf + c + 1e-8f);
        ws_dtw[(size_t)b * NW_ + q] = qtw[(size_t)b * NW_ + q] * dtw;
    }
}

// ---------------------------------------------------------------------------
// Final: s[b] = sum_q ws_dtw[b,q].  One wave per batch.
// ---------------------------------------------------------------------------
__global__ __launch_bounds__(64) void final_kernel(
    const float* __restrict__ ws_dtw, float* __restrict__ out)
{
    const int b = blockIdx.x;
    const int lane = threadIdx.x;
    float4 v = *(const float4*)(ws_dtw + (size_t)b * NW_ + lane * 4);
    float s = v.x + v.y + v.z + v.w;
#pragma unroll
    for (int off = 32; off; off >>= 1) s += __shfl_xor(s, off);
    if (lane == 0) out[b] = s;
}

extern "C" void kernel_launch(void* const* d_in, const int* in_sizes, int n_in,
                              void* d_out, int out_size, void* d_ws, size_t ws_size,
                              hipStream_t stream)
{
    const float* q_rep = (const float*)d_in[0];
    const float* d_rep = (const float*)d_in[1];
    const float* qtw   = (const float*)d_in[2];
    const int*   q_ids = (const int*)d_in[3];
    const int*   d_ids = (const int*)d_in[4];
    const int*   d_tfs = (const int*)d_in[5];

    float* out = (float*)d_out;
    float* S   = out + B_;              // d_expanded_tf, [B, NW, NW]
    float* ws_dtw = (float*)d_ws;       // [B, NW] floats = 64 KiB

    dim3 ggrid(NW_ / 64, NW_ / 64, B_); // 4 x 4 x 64 = 1024 blocks
    gemm_kernel<<<ggrid, 64, 0, stream>>>(q_rep, d_rep, q_ids, d_ids, S);

    dim3 sgrid(NW_, B_);                // 16384 blocks
    score_kernel<<<sgrid, 64, 0, stream>>>(S, q_ids, d_ids, d_tfs, qtw, ws_dtw);

    final_kernel<<<B_, 64, 0, stream>>>(ws_dtw, out);
}

// Round 2
// 171.296 us; speedup vs baseline: 1.0410x; 1.0410x over previous
//
#include <hip/hip_runtime.h>
#include <hip/hip_bf16.h>

#define B_   64
#define NW_  256
#define H_   768

#define ALPHA_BETA     (0.1f / 768.0f)   // ALPHA*BETA
#define OMB_           0.9f              // 1 - BETA
#define K1_            0.1f
#define BP_            1.2f
#define AVDL_          50.0f

typedef __bf16 bf16x8 __attribute__((ext_vector_type(8)));
typedef float  f32x4  __attribute__((ext_vector_type(4)));

// ---------------------------------------------------------------------------
// Fused GEMM + row-score kernel.
// Block = 256 threads = 4 waves, computes one 64x64 tile of S[b].
// Split-K inside the block: wave w handles K-slice [w*192, (w+1)*192).
// Wave-PRIVATE LDS staging -> no barriers in the K-loop (16 waves/CU TLP
// hides global latency). Partials combined through an LDS tile at the end,
// then the block stores S and atomicAdds per-q score partials.
// ---------------------------------------------------------------------------
__global__ __launch_bounds__(256, 4) void gemm_score_kernel(
    const float* __restrict__ q_rep, const float* __restrict__ d_rep,
    const int* __restrict__ q_ids, const int* __restrict__ d_ids,
    const int* __restrict__ d_tfs,
    float* __restrict__ S, float* __restrict__ ws_etdf)
{
    // 40 KB LDS: 4 wave-private staging regions of 10 KB (A,B: 64 rows x
    // (32+8 pad) bf16 each). Epilogue aliases: T[64][68] f32 (17408 B) +
    // q keys (1 KB) + d keys (1 KB) + tf (256 B).
    __shared__ __align__(16) unsigned char lds[40960];

    const int tid  = threadIdx.x;
    const int wave = tid >> 6;
    const int lane = tid & 63;
    const int b  = blockIdx.z;
    const int m0 = blockIdx.y * 64;
    const int n0 = blockIdx.x * 64;

    __bf16* As = (__bf16*)(lds + wave * 10240);          // [64][40]
    __bf16* Bs = As + 64 * 40;                           // [64][40]

    const int rq  = lane >> 2;          // 0..15: row within 16-row group
    const int seg = lane & 3;           // 0..3 : 8-float segment of BK=32

    // Null masks for the rows this lane stages (same rows every chunk).
    float mA[4], mB[4];
#pragma unroll
    for (int it = 0; it < 4; ++it) {
        const int row = it * 16 + rq;
        int4 qa = *(const int4*)(q_ids + ((size_t)b * NW_ + m0 + row) * 4);
        mA[it] = (qa.x == 0 && qa.y == 0 && qa.z == 0 && qa.w == 0) ? 0.f : 1.f;
        int4 da = *(const int4*)(d_ids + ((size_t)b * NW_ + n0 + row) * 4);
        mB[it] = (da.x == 0 && da.y == 0 && da.z == 0 && da.w == 0) ? 0.f : 1.f;
    }

    const float* Abase = q_rep + ((size_t)b * NW_ + m0) * H_ + wave * 192;
    const float* Bbase = d_rep + ((size_t)b * NW_ + n0) * H_ + wave * 192;

    f32x4 acc[4][4];
#pragma unroll
    for (int i = 0; i < 4; ++i)
#pragma unroll
        for (int j = 0; j < 4; ++j)
            acc[i][j] = (f32x4){0.f, 0.f, 0.f, 0.f};

    const int fr = lane & 15;           // frag row in 16x16 tile
    const int fk = (lane >> 4) * 8;     // frag k offset (quad*8)

    // K-loop: 6 chunks of 32 per wave. No __syncthreads inside — staging is
    // wave-private; compiler-inserted vmcnt/lgkmcnt give in-wave ordering.
    for (int kc = 0; kc < 6; ++kc) {
        float4 ra[8], rb[8];
#pragma unroll
        for (int it = 0; it < 4; ++it) {
            const float* pa = Abase + (size_t)(it * 16 + rq) * H_ + kc * 32 + seg * 8;
            ra[it * 2]     = *(const float4*)pa;
            ra[it * 2 + 1] = *(const float4*)(pa + 4);
            const float* pb = Bbase + (size_t)(it * 16 + rq) * H_ + kc * 32 + seg * 8;
            rb[it * 2]     = *(const float4*)pb;
            rb[it * 2 + 1] = *(const float4*)(pb + 4);
        }
#pragma unroll
        for (int it = 0; it < 4; ++it) {
            const int row = it * 16 + rq;
            float4 x = ra[it * 2], y = ra[it * 2 + 1];
            float m = mA[it];
            bf16x8 va;
            va[0] = (__bf16)(x.x * m); va[1] = (__bf16)(x.y * m);
            va[2] = (__bf16)(x.z * m); va[3] = (__bf16)(x.w * m);
            va[4] = (__bf16)(y.x * m); va[5] = (__bf16)(y.y * m);
            va[6] = (__bf16)(y.z * m); va[7] = (__bf16)(y.w * m);
            *(bf16x8*)&As[row * 40 + seg * 8] = va;

            float4 u = rb[it * 2], v = rb[it * 2 + 1];
            float n = mB[it];
            bf16x8 vb;
            vb[0] = (__bf16)(u.x * n); vb[1] = (__bf16)(u.y * n);
            vb[2] = (__bf16)(u.z * n); vb[3] = (__bf16)(u.w * n);
            vb[4] = (__bf16)(v.x * n); vb[5] = (__bf16)(v.y * n);
            vb[6] = (__bf16)(v.z * n); vb[7] = (__bf16)(v.w * n);
            *(bf16x8*)&Bs[row * 40 + seg * 8] = vb;
        }
        bf16x8 af[4], bfr[4];
#pragma unroll
        for (int t = 0; t < 4; ++t) {
            af[t]  = *(bf16x8*)&As[(t * 16 + fr) * 40 + fk];
            bfr[t] = *(bf16x8*)&Bs[(t * 16 + fr) * 40 + fk];
        }
#pragma unroll
        for (int i = 0; i < 4; ++i)
#pragma unroll
            for (int j = 0; j < 4; ++j)
                acc[i][j] = __builtin_amdgcn_mfma_f32_16x16x32_bf16(
                    af[i], bfr[j], acc[i][j], 0, 0, 0);
    }

    __syncthreads();                    // all staging dead; begin epilogue

    float* T     = (float*)lds;                 // [64][68]
    int4*  qk_s  = (int4*)(lds + 17408);        // 64 q id-keys
    int4*  dk_s  = (int4*)(lds + 18432);        // 64 d id-keys
    float* tf_s  = (float*)(lds + 19456);       // 64 tf values

    if (tid < 64)
        qk_s[tid] = *(const int4*)(q_ids + ((size_t)b * NW_ + m0 + tid) * 4);
    else if (tid < 128)
        dk_s[tid - 64] = *(const int4*)(d_ids + ((size_t)b * NW_ + n0 + tid - 64) * 4);
    else if (tid < 192)
        tf_s[tid - 128] = (float)d_tfs[(size_t)b * NW_ + n0 + tid - 128];

    // Serialized cross-wave combine of the 4 K-slice partials.
    const int cn  = lane & 15;
    const int rb4 = (lane >> 4) * 4;
    for (int w = 0; w < 4; ++w) {
        if (wave == w) {
#pragma unroll
            for (int i = 0; i < 4; ++i)
#pragma unroll
                for (int j = 0; j < 4; ++j)
#pragma unroll
                    for (int r = 0; r < 4; ++r) {
                        const int row = i * 16 + rb4 + r;
                        const int col = j * 16 + cn;
                        if (w == 0) T[row * 68 + col]  = acc[i][j][r];
                        else        T[row * 68 + col] += acc[i][j][r];
                    }
        }
        __syncthreads();
    }

    // Store S (coalesced float4) and accumulate per-q score partials.
    const int r  = tid >> 2;            // 0..63: row within tile
    const int qq = tid & 3;             // quarter of the 64 cols
    const float* Tr = &T[r * 68 + qq * 16];
    float* Srow = S + ((size_t)b * NW_ + m0 + r) * NW_ + n0 + qq * 16;
#pragma unroll
    for (int i = 0; i < 4; ++i)
        ((float4*)Srow)[i] = ((const float4*)Tr)[i];

    int4 qk = qk_s[r];
    float ps = 0.f;
#pragma unroll
    for (int i = 0; i < 16; ++i) {
        const int c = qq * 16 + i;
        int4 dk = dk_s[c];
        float em = (dk.x == qk.x && dk.y == qk.y &&
                    dk.z == qk.z && dk.w == qk.w) ? OMB_ : 0.f;
        ps += (ALPHA_BETA * Tr[i] + em) * tf_s[c];
    }
    ps += __shfl_xor(ps, 1);
    ps += __shfl_xor(ps, 2);
    if (qq == 0)
        atomicAdd(&ws_etdf[(size_t)b * NW_ + m0 + r], ps);
}

// ---------------------------------------------------------------------------
// Final: per batch, dl = sum(tf); dtw = 1.1*etdf/(etdf + K1*(1-Bp+Bp*dl/AVDL)
// + 1e-8); s[b] = sum_q qtw*dtw.  One wave per batch.
// ---------------------------------------------------------------------------
__global__ __launch_bounds__(64) void final_kernel(
    const float* __restrict__ ws_etdf, const int* __restrict__ d_tfs,
    const float* __restrict__ qtw, float* __restrict__ out)
{
    const int b = blockIdx.x;
    const int lane = threadIdx.x;

    float4 ev = *(const float4*)(ws_etdf + (size_t)b * NW_ + lane * 4);
    int4  tf4 = *(const int4*)(d_tfs   + (size_t)b * NW_ + lane * 4);
    float4 qv = *(const float4*)(qtw    + (size_t)b * NW_ + lane * 4);

    float dl = (float)(tf4.x + tf4.y + tf4.z + tf4.w);
#pragma unroll
    for (int off = 32; off; off >>= 1) dl += __shfl_xor(dl, off);

    const float c = K1_ * (1.f - BP_ + BP_ * dl / AVDL_);
    float ew[4] = {ev.x, ev.y, ev.z, ev.w};
    float qw[4] = {qv.x, qv.y, qv.z, qv.w};
    float s = 0.f;
#pragma unroll
    for (int j = 0; j < 4; ++j)
        s += qw[j] * (ew[j] * (1.f + K1_)) / (ew[j] + c + 1e-8f);
#pragma unroll
    for (int off = 32; off; off >>= 1) s += __shfl_xor(s, off);
    if (lane == 0) out[b] = s;
}

extern "C" void kernel_launch(void* const* d_in, const int* in_sizes, int n_in,
                              void* d_out, int out_size, void* d_ws, size_t ws_size,
                              hipStream_t stream)
{
    const float* q_rep = (const float*)d_in[0];
    const float* d_rep = (const float*)d_in[1];
    const float* qtw   = (const float*)d_in[2];
    const int*   q_ids = (const int*)d_in[3];
    const int*   d_ids = (const int*)d_in[4];
    const int*   d_tfs = (const int*)d_in[5];

    float* out = (float*)d_out;
    float* S   = out + B_;              // d_expanded_tf, [B, NW, NW]
    float* ws_etdf = (float*)d_ws;      // [B, NW] f32 = 64 KiB scratch

    hipMemsetAsync(ws_etdf, 0, (size_t)B_ * NW_ * sizeof(float), stream);

    dim3 ggrid(NW_ / 64, NW_ / 64, B_); // 4 x 4 x 64 = 1024 blocks of 256
    gemm_score_kernel<<<ggrid, 256, 0, stream>>>(q_rep, d_rep, q_ids, d_ids,
                                                 d_tfs, S, ws_etdf);

    final_kernel<<<B_, 64, 0, stream>>>(ws_etdf, d_tfs, qtw, out);
}